// Round 1
// baseline (11063.006 us; speedup 1.0000x reference)
//
#include <hip/hip_runtime.h>

// ESN forward, teacher-forced, T=4096 steps of a strictly sequential recurrence:
//   s[t] = tanh(w @ s[t-1] + w_in @ in[t] + w_fb @ out[t-1]) + 1e-3*(nu[t]-0.5)
// Strategy: ONE persistent kernel, 256 blocks x 256 threads.
//   - block b owns rows [8b, 8b+8); thread owns 8 rows x 8 cols of w in VGPRs.
//   - state exchanged via 8-byte {value, step-tag} words at agent scope (sc1),
//     double-buffered; consumers spin on tags of exactly the words they need.
//   - w_in / w_feedb folded in as one extra "virtual column" per thread (tid<96).

#define N_RES   2048
#define N_IN    64
#define N_OUT   32
#define T_STEPS 4096
#define NOISEC  0.001f
#define NBLK    256
#define NTHR    256
#define RPB     8     // rows per block  (N_RES / NBLK)
#define CPT     8     // cols per thread (N_RES / NTHR)

__global__ void esn_init(unsigned long long* __restrict__ slots) {
    const int i = blockIdx.x * blockDim.x + threadIdx.x;
    if (i < 2 * N_RES)
        __hip_atomic_store(slots + i, 0ull, __ATOMIC_RELAXED, __HIP_MEMORY_SCOPE_AGENT);
}

__global__ __launch_bounds__(NTHR, 1)
void esn_run(const float* __restrict__ inputs,    // T x 64
             const float* __restrict__ outputs,   // T x 32
             const float* __restrict__ w,         // 2048 x 2048
             const float* __restrict__ w_in,      // 2048 x 64
             const float* __restrict__ w_feedb,   // 2048 x 32
             const float* __restrict__ out_w,     // 32 x 2048
             const float* __restrict__ out_b,     // 32
             const float* __restrict__ noise_u,   // T x 2048
             float* __restrict__ d_out,           // 32 + 2048
             unsigned long long* __restrict__ slots) { // 2 x 2048 tagged words
    const int tid  = threadIdx.x;
    const int blk  = blockIdx.x;
    const int row8 = blk * RPB;
    const int wav  = tid >> 6;

    __shared__ float red[4][RPB];

    // ---- persistent W fragment: 8 rows x my 8 contiguous columns ----
    float wrc[RPB * CPT];
    #pragma unroll
    for (int r = 0; r < RPB; ++r) {
        const float* wp = w + (size_t)(row8 + r) * N_RES + tid * CPT;
        const float4 u0 = *reinterpret_cast<const float4*>(wp);
        const float4 u1 = *reinterpret_cast<const float4*>(wp + 4);
        wrc[r*8+0]=u0.x; wrc[r*8+1]=u0.y; wrc[r*8+2]=u0.z; wrc[r*8+3]=u0.w;
        wrc[r*8+4]=u1.x; wrc[r*8+5]=u1.y; wrc[r*8+6]=u1.z; wrc[r*8+7]=u1.w;
    }
    // ---- persistent w_in / w_feedb fragment: one virtual column per thread ----
    float wex[RPB];
    #pragma unroll
    for (int r = 0; r < RPB; ++r) {
        float v = 0.f;
        if (tid < N_IN)              v = w_in[(row8 + r) * N_IN + tid];
        else if (tid < N_IN + N_OUT) v = w_feedb[(row8 + r) * N_OUT + (tid - N_IN)];
        wex[r] = v;
    }

    for (int t = 1; t < T_STEPS; ++t) {
        // off-critical-path operands (read-only data, plain cached loads)
        float xv = 0.f;
        if (tid < N_IN)              xv = inputs[t * N_IN + tid];
        else if (tid < N_IN + N_OUT) xv = outputs[(t - 1) * N_OUT + (tid - N_IN)];
        float nu = 0.f;
        if (tid < RPB) nu = noise_u[(size_t)t * N_RES + row8 + tid];

        // ---- wait for + load my 8 tagged state words (agent scope, bypass L2) ----
        const unsigned long long* sl =
            slots + (size_t)((t - 1) & 1) * N_RES + tid * CPT;
        const unsigned need = (unsigned)(t - 1);
        unsigned long long vv[CPT];
        #pragma unroll
        for (int i = 0; i < CPT; ++i)
            vv[i] = __hip_atomic_load(sl + i, __ATOMIC_RELAXED, __HIP_MEMORY_SCOPE_AGENT);
        for (;;) {
            unsigned mn = 0xffffffffu;
            #pragma unroll
            for (int i = 0; i < CPT; ++i) {
                const unsigned tg = (unsigned)(vv[i] >> 32);
                mn = (tg < mn) ? tg : mn;
            }
            if (mn >= need) break;
            #pragma unroll
            for (int i = 0; i < CPT; ++i)
                if ((unsigned)(vv[i] >> 32) < need)
                    vv[i] = __hip_atomic_load(sl + i, __ATOMIC_RELAXED, __HIP_MEMORY_SCOPE_AGENT);
        }

        // ---- partial dot products: 8 rows over my 8 columns ----
        float acc[RPB];
        #pragma unroll
        for (int r = 0; r < RPB; ++r) acc[r] = 0.f;
        #pragma unroll
        for (int i = 0; i < CPT; ++i) {
            const float sv = __uint_as_float((unsigned)(vv[i] & 0xffffffffu));
            #pragma unroll
            for (int r = 0; r < RPB; ++r)
                acc[r] = fmaf(wrc[r*8+i], sv, acc[r]);
        }
        #pragma unroll
        for (int r = 0; r < RPB; ++r) acc[r] = fmaf(wex[r], xv, acc[r]);

        // ---- reduce: 64 lanes (butterfly) then 4 waves (LDS) ----
        #pragma unroll
        for (int m = 1; m < 64; m <<= 1) {
            #pragma unroll
            for (int r = 0; r < RPB; ++r)
                acc[r] += __shfl_xor(acc[r], m, 64);
        }
        if ((tid & 63) == 0) {
            #pragma unroll
            for (int r = 0; r < RPB; ++r) red[wav][r] = acc[r];
        }
        __syncthreads();
        if (tid < RPB) {
            const float tot = red[0][tid] + red[1][tid] + red[2][tid] + red[3][tid];
            const float val = tanhf(tot) + NOISEC * (nu - 0.5f);
            const unsigned long long pk =
                ((unsigned long long)(unsigned)t << 32) |
                (unsigned long long)__float_as_uint(val);
            __hip_atomic_store(slots + (size_t)(t & 1) * N_RES + row8 + tid, pk,
                               __ATOMIC_RELAXED, __HIP_MEMORY_SCOPE_AGENT);
            if (t == T_STEPS - 1) d_out[32 + row8 + tid] = val;
        }
        __syncthreads(); // protect red[][] WAR before next iteration
    }

    // ---- epilogue: block 0 computes readout = out_w @ s_final + out_b ----
    if (blk == 0) {
        const unsigned long long* sf = slots + (size_t)((T_STEPS - 1) & 1) * N_RES;
        const int r2 = tid >> 3, j2 = tid & 7;     // 32 rows x 8 lanes
        const unsigned need = (unsigned)(T_STEPS - 1);
        float acc = 0.f;
        for (int c0 = 0; c0 < N_RES / 8; c0 += 8) { // 256 cols per lane, 8 at a time
            const unsigned long long* p = sf + j2 * (N_RES / 8) + c0;
            unsigned long long vv[8];
            #pragma unroll
            for (int i = 0; i < 8; ++i)
                vv[i] = __hip_atomic_load(p + i, __ATOMIC_RELAXED, __HIP_MEMORY_SCOPE_AGENT);
            for (;;) {
                unsigned mn = 0xffffffffu;
                #pragma unroll
                for (int i = 0; i < 8; ++i) {
                    const unsigned tg = (unsigned)(vv[i] >> 32);
                    mn = (tg < mn) ? tg : mn;
                }
                if (mn >= need) break;
                #pragma unroll
                for (int i = 0; i < 8; ++i)
                    if ((unsigned)(vv[i] >> 32) < need)
                        vv[i] = __hip_atomic_load(p + i, __ATOMIC_RELAXED, __HIP_MEMORY_SCOPE_AGENT);
            }
            #pragma unroll
            for (int i = 0; i < 8; ++i) {
                const float sv = __uint_as_float((unsigned)(vv[i] & 0xffffffffu));
                acc = fmaf(out_w[r2 * N_RES + j2 * (N_RES / 8) + c0 + i], sv, acc);
            }
        }
        #pragma unroll
        for (int m = 1; m < 8; m <<= 1) acc += __shfl_xor(acc, m, 64);
        if (j2 == 0) d_out[r2] = acc + out_b[r2];
    }
}

extern "C" void kernel_launch(void* const* d_in, const int* in_sizes, int n_in,
                              void* d_out, int out_size, void* d_ws, size_t ws_size,
                              hipStream_t stream) {
    const float* inputs  = (const float*)d_in[0];
    const float* outputs = (const float*)d_in[1];
    const float* w       = (const float*)d_in[2];
    const float* w_in    = (const float*)d_in[3];
    const float* w_feedb = (const float*)d_in[4];
    const float* out_w   = (const float*)d_in[5];
    const float* out_b   = (const float*)d_in[6];
    const float* noise_u = (const float*)d_in[7];
    unsigned long long* slots = (unsigned long long*)d_ws; // 2*2048*8 B = 32 KB

    // re-init tags every call: d_ws is NOT re-poisoned between graph replays,
    // and stale tags from a previous replay would be read as valid.
    esn_init<<<(2 * N_RES + NTHR - 1) / NTHR, NTHR, 0, stream>>>(slots);
    esn_run<<<NBLK, NTHR, 0, stream>>>(inputs, outputs, w, w_in, w_feedb,
                                       out_w, out_b, noise_u,
                                       (float*)d_out, slots);
}

// Round 2
// 9780.170 us; speedup vs baseline: 1.1312x; 1.1312x over previous
//
#include <hip/hip_runtime.h>

// ESN forward, teacher-forced: s[t] = tanh(w@s[t-1] + w_in@in[t] + w_fb@out[t-1]) + 1e-3*(nu[t]-0.5)
// One persistent kernel, 128 blocks x 256 threads.
//   - block owns 16 rows; thread owns 16 rows x 8 cols of w, PINNED in VGPRs via
//     empty-asm keep-alive each step (defeats rematerialization-from-memory, which
//     round-1 counters proved: VGPR_Count=60 < the 90+ needed => w was re-loaded
//     from L2 every step and the loop was load-latency-bound).
//   - state exchanged via 8-byte {fp32, step-tag} words at agent scope (sc1),
//     double-buffered; tag fused with data => no producer fence, no flag RT.
//   - reduction: halving exchange (masks 1,2,4) then butterfly (8,16,32): 20 shfls.

#define N_RES   2048
#define N_IN    64
#define N_OUT   32
#define T_STEPS 4096
#define NOISEC  0.001f
#define NBLK    128
#define NTHR    256
#define RPB     16    // rows per block  (N_RES / NBLK)
#define CPT     8     // cols per thread (N_RES / NTHR)

typedef float f32x4 __attribute__((ext_vector_type(4)));

#define PIN8(a,b,c,d,e,f,g,h) \
    asm volatile("" : "+v"(a),"+v"(b),"+v"(c),"+v"(d),"+v"(e),"+v"(f),"+v"(g),"+v"(h))

__global__ void esn_init(unsigned long long* __restrict__ slots) {
    const int i = blockIdx.x * blockDim.x + threadIdx.x;
    if (i < 2 * N_RES)
        __hip_atomic_store(slots + i, 0ull, __ATOMIC_RELAXED, __HIP_MEMORY_SCOPE_AGENT);
}

__global__ __launch_bounds__(NTHR, 1)
void esn_run(const float* __restrict__ inputs,    // T x 64
             const float* __restrict__ outputs,   // T x 32
             const float* __restrict__ w,         // 2048 x 2048
             const float* __restrict__ w_in,      // 2048 x 64
             const float* __restrict__ w_feedb,   // 2048 x 32
             const float* __restrict__ out_w,     // 32 x 2048
             const float* __restrict__ out_b,     // 32
             const float* __restrict__ noise_u,   // T x 2048
             float* __restrict__ d_out,           // 32 + 2048
             unsigned long long* __restrict__ slots) { // 2 x 2048 tagged words
    const int tid  = threadIdx.x;
    const int blk  = blockIdx.x;
    const int row0 = blk * RPB;
    const int wav  = tid >> 6;
    const int lan  = tid & 63;

    __shared__ float red[4][RPB];

    // ---- persistent W fragment: 16 rows x my 8 contiguous columns (32 f32x4) ----
    f32x4 wv[RPB][2];
    #pragma unroll
    for (int r = 0; r < RPB; ++r) {
        const float* wp = w + (size_t)(row0 + r) * N_RES + tid * CPT;
        wv[r][0] = *reinterpret_cast<const f32x4*>(wp);
        wv[r][1] = *reinterpret_cast<const f32x4*>(wp + 4);
    }
    // ---- w_in / w_feedb: one virtual column per thread (tid<96), row-indexed ----
    f32x4 wex[4];
    #pragma unroll
    for (int r = 0; r < RPB; ++r) {
        float v = 0.f;
        if (tid < N_IN)              v = w_in[(row0 + r) * N_IN + tid];
        else if (tid < N_IN + N_OUT) v = w_feedb[(row0 + r) * N_OUT + (tid - N_IN)];
        wex[r >> 2][r & 3] = v;
    }

    for (int t = 1; t < T_STEPS; ++t) {
        // keep W + wex resident in VGPRs: pretend asm rewrites them each step,
        // so the compiler cannot rematerialize them from global memory.
        PIN8(wv[0][0], wv[0][1], wv[1][0], wv[1][1], wv[2][0], wv[2][1], wv[3][0], wv[3][1]);
        PIN8(wv[4][0], wv[4][1], wv[5][0], wv[5][1], wv[6][0], wv[6][1], wv[7][0], wv[7][1]);
        PIN8(wv[8][0], wv[8][1], wv[9][0], wv[9][1], wv[10][0], wv[10][1], wv[11][0], wv[11][1]);
        PIN8(wv[12][0], wv[12][1], wv[13][0], wv[13][1], wv[14][0], wv[14][1], wv[15][0], wv[15][1]);
        asm volatile("" : "+v"(wex[0]), "+v"(wex[1]), "+v"(wex[2]), "+v"(wex[3]));

        // off-critical-path operands (issued before the poll; overlap with it)
        float xv = 0.f;
        if (tid < N_IN)              xv = inputs[t * N_IN + tid];
        else if (tid < N_IN + N_OUT) xv = outputs[(t - 1) * N_OUT + (tid - N_IN)];
        float nu = 0.f;
        if (tid < RPB) nu = noise_u[(size_t)t * N_RES + row0 + tid];

        // ---- wait for + load my 8 tagged state words (agent scope) ----
        const unsigned long long* sl =
            slots + (size_t)((t - 1) & 1) * N_RES + tid * CPT;
        const unsigned need = (unsigned)(t - 1);
        unsigned long long vv[CPT];
        #pragma unroll
        for (int i = 0; i < CPT; ++i)
            vv[i] = __hip_atomic_load(sl + i, __ATOMIC_RELAXED, __HIP_MEMORY_SCOPE_AGENT);
        for (;;) {
            unsigned mn = 0xffffffffu;
            #pragma unroll
            for (int i = 0; i < CPT; ++i) {
                const unsigned tg = (unsigned)(vv[i] >> 32);
                mn = (tg < mn) ? tg : mn;
            }
            if (mn >= need) break;
            #pragma unroll
            for (int i = 0; i < CPT; ++i)
                if ((unsigned)(vv[i] >> 32) < need)
                    vv[i] = __hip_atomic_load(sl + i, __ATOMIC_RELAXED, __HIP_MEMORY_SCOPE_AGENT);
        }

        // ---- partial dot products: 16 rows over my 8 columns (128 FMA) ----
        float acc[RPB];
        #pragma unroll
        for (int r = 0; r < RPB; ++r) acc[r] = 0.f;
        #pragma unroll
        for (int i = 0; i < CPT; ++i) {
            const float sv = __uint_as_float((unsigned)(vv[i] & 0xffffffffu));
            #pragma unroll
            for (int r = 0; r < RPB; ++r)
                acc[r] = fmaf(wv[r][i >> 2][i & 3], sv, acc[r]);
        }
        #pragma unroll
        for (int r = 0; r < RPB; ++r)
            acc[r] = fmaf(wex[r >> 2][r & 3], xv, acc[r]);

        // ---- reduce within wave: halving exchange then butterfly (20 shfls) ----
        {   // mask 1: 16 -> 8 values/lane
            const bool b = (lan & 1);
            #pragma unroll
            for (int r = 0; r < 8; ++r) {
                const float send = b ? acc[r] : acc[r + 8];
                const float got  = __shfl_xor(send, 1, 64);
                acc[r] = (b ? acc[r + 8] : acc[r]) + got;
            }
        }
        {   // mask 2: 8 -> 4
            const bool b = (lan >> 1) & 1;
            #pragma unroll
            for (int r = 0; r < 4; ++r) {
                const float send = b ? acc[r] : acc[r + 4];
                const float got  = __shfl_xor(send, 2, 64);
                acc[r] = (b ? acc[r + 4] : acc[r]) + got;
            }
        }
        {   // mask 4: 4 -> 2
            const bool b = (lan >> 2) & 1;
            #pragma unroll
            for (int r = 0; r < 2; ++r) {
                const float send = b ? acc[r] : acc[r + 2];
                const float got  = __shfl_xor(send, 4, 64);
                acc[r] = (b ? acc[r + 2] : acc[r]) + got;
            }
        }
        #pragma unroll
        for (int m = 8; m < 64; m <<= 1) {
            acc[0] += __shfl_xor(acc[0], m, 64);
            acc[1] += __shfl_xor(acc[1], m, 64);
        }
        // lane l (l<8) holds rows rb, rb+1 with rb = 8*b0 + 4*b1 + 2*b2
        if (lan < 8) {
            const int rb = 8 * (lan & 1) + 4 * ((lan >> 1) & 1) + 2 * ((lan >> 2) & 1);
            red[wav][rb]     = acc[0];
            red[wav][rb + 1] = acc[1];
        }
        __syncthreads();
        if (tid < RPB) {
            const float tot = red[0][tid] + red[1][tid] + red[2][tid] + red[3][tid];
            const float val = tanhf(tot) + NOISEC * (nu - 0.5f);
            const unsigned long long pk =
                ((unsigned long long)(unsigned)t << 32) |
                (unsigned long long)__float_as_uint(val);
            __hip_atomic_store(slots + (size_t)(t & 1) * N_RES + row0 + tid, pk,
                               __ATOMIC_RELAXED, __HIP_MEMORY_SCOPE_AGENT);
            if (t == T_STEPS - 1) d_out[32 + row0 + tid] = val;
        }
        __syncthreads(); // protect red[][] WAR before next iteration
    }

    // ---- epilogue: block 0 computes readout = out_w @ s_final + out_b ----
    if (blk == 0) {
        const unsigned long long* sf = slots + (size_t)((T_STEPS - 1) & 1) * N_RES;
        const int r2 = tid >> 3, j2 = tid & 7;     // 32 rows x 8 lanes
        const unsigned need = (unsigned)(T_STEPS - 1);
        float acc = 0.f;
        for (int c0 = 0; c0 < N_RES / 8; c0 += 8) { // 256 cols per lane, 8 at a time
            const unsigned long long* p = sf + j2 * (N_RES / 8) + c0;
            unsigned long long vv[8];
            #pragma unroll
            for (int i = 0; i < 8; ++i)
                vv[i] = __hip_atomic_load(p + i, __ATOMIC_RELAXED, __HIP_MEMORY_SCOPE_AGENT);
            for (;;) {
                unsigned mn = 0xffffffffu;
                #pragma unroll
                for (int i = 0; i < 8; ++i) {
                    const unsigned tg = (unsigned)(vv[i] >> 32);
                    mn = (tg < mn) ? tg : mn;
                }
                if (mn >= need) break;
                #pragma unroll
                for (int i = 0; i < 8; ++i)
                    if ((unsigned)(vv[i] >> 32) < need)
                        vv[i] = __hip_atomic_load(p + i, __ATOMIC_RELAXED, __HIP_MEMORY_SCOPE_AGENT);
            }
            #pragma unroll
            for (int i = 0; i < 8; ++i) {
                const float sv = __uint_as_float((unsigned)(vv[i] & 0xffffffffu));
                acc = fmaf(out_w[r2 * N_RES + j2 * (N_RES / 8) + c0 + i], sv, acc);
            }
        }
        #pragma unroll
        for (int m = 1; m < 8; m <<= 1) acc += __shfl_xor(acc, m, 64);
        if (j2 == 0) d_out[r2] = acc + out_b[r2];
    }
}

extern "C" void kernel_launch(void* const* d_in, const int* in_sizes, int n_in,
                              void* d_out, int out_size, void* d_ws, size_t ws_size,
                              hipStream_t stream) {
    const float* inputs  = (const float*)d_in[0];
    const float* outputs = (const float*)d_in[1];
    const float* w       = (const float*)d_in[2];
    const float* w_in    = (const float*)d_in[3];
    const float* w_feedb = (const float*)d_in[4];
    const float* out_w   = (const float*)d_in[5];
    const float* out_b   = (const float*)d_in[6];
    const float* noise_u = (const float*)d_in[7];
    unsigned long long* slots = (unsigned long long*)d_ws; // 2*2048*8 B = 32 KB

    // re-init tags every call: d_ws is NOT re-poisoned between graph replays,
    // and stale tags from a previous replay would be read as valid.
    esn_init<<<(2 * N_RES + NTHR - 1) / NTHR, NTHR, 0, stream>>>(slots);
    esn_run<<<NBLK, NTHR, 0, stream>>>(inputs, outputs, w, w_in, w_feedb,
                                       out_w, out_b, noise_u,
                                       (float*)d_out, slots);
}